// Round 12
// baseline (246.938 us; speedup 1.0000x reference)
//
#include <hip/hip_runtime.h>
#include <math.h>

#define BB   2
#define CFI  32
#define NN   36864          // 192*192
#define NUMM 16

// workspace: Y at ws[0..], Z at ws[ZOFS..]  (point-major [B*N][32] each)
#define ZOFS (BB * NN * CFI)

typedef __attribute__((ext_vector_type(8))) short short8;   // 8 bf16 (4 VGPRs)
typedef __attribute__((ext_vector_type(4))) float f4;       // 4 f32

static __device__ __forceinline__ f4 mm16(short8 a, short8 b, f4 c) {
    return __builtin_amdgcn_mfma_f32_16x16x32_bf16(a, b, c, 0, 0, 0);
}

// tanh-form gelu: x * sigmoid(1.595769x + 0.0713548x^3), exp2-folded.
static __device__ __forceinline__ float gelu_fast(float x) {
    const float x2  = x * x;
    const float q   = fmaf(-0.10294310f, x2, -2.30211813f);
    const float e   = exp2f(q * x);
    const float r   = __builtin_amdgcn_rcpf(e + 1.0f);
    return x * r;
}

static __device__ __forceinline__ unsigned bf16_rne_bits(float x) {
    unsigned u = __builtin_bit_cast(unsigned, x);
    return u + 0x7fffu + ((u >> 16) & 1u);
}
static __device__ __forceinline__ void split_pack(float x0, float x1,
                                                  unsigned& hi, unsigned& lo) {
    unsigned r0 = bf16_rne_bits(x0);
    unsigned r1 = bf16_rne_bits(x1);
    float h0 = __builtin_bit_cast(float, r0 & 0xffff0000u);
    float h1 = __builtin_bit_cast(float, r1 & 0xffff0000u);
    hi = (r0 >> 16) | (r1 & 0xffff0000u);
    unsigned s0 = bf16_rne_bits(x0 - h0);
    unsigned s1 = bf16_rne_bits(x1 - h1);
    lo = (s0 >> 16) | (s1 & 0xffff0000u);
}

// cheap round-half-up bf16 pair pack (activations)
static __device__ __forceinline__ unsigned pack2(float a, float b) {
    unsigned ua = __builtin_bit_cast(unsigned, a) + 0x8000u;
    unsigned ub = __builtin_bit_cast(unsigned, b) + 0x8000u;
    return (ua >> 16) | (ub & 0xffff0000u);
}

union UV { unsigned u[4]; short8 v; };

// ---- kernel A: per-point Y/Z precompute (layer-1 split) -- unchanged ------
__global__ __launch_bounds__(256) void yz_kernel(
    const float* __restrict__ If, const float* __restrict__ Pf,
    const float* __restrict__ W1, const float* __restrict__ g1,
    const float* __restrict__ b1, const float* __restrict__ m1,
    const float* __restrict__ v1,
    float* __restrict__ wsYZ)
{
    __shared__ float wy[1024], wz[1024], wp[32], bt1[32];
    for (int i = threadIdx.x; i < 1024; i += 256) {
        int o = i >> 5, c = i & 31;
        float inv = g1[o] * rsqrtf(v1[o] + 1e-5f);
        wy[i] = W1[o * 67 + c]      * inv;
        wz[i] = W1[o * 67 + 32 + c] * inv;
    }
    if (threadIdx.x < 32) {
        int o = threadIdx.x;
        float inv = g1[o] * rsqrtf(v1[o] + 1e-5f);
        wp[o]  = W1[o * 67 + 64] * inv;
        bt1[o] = b1[o] - m1[o] * inv;
    }
    __syncthreads();

    const int r  = threadIdx.x & 3;
    const int p  = blockIdx.x * 64 + (threadIdx.x >> 2);
    const int b  = p / NN, n = p - b * NN;
    const int o0 = r * 8;
    const float* ifp = If + (size_t)b * CFI * NN + n;

    float v[32];
#pragma unroll
    for (int c = 0; c < 32; c++) v[c] = ifp[(size_t)c * NN];
    const float pf = Pf[p];

    float accY[8], accZ[8];
#pragma unroll
    for (int j = 0; j < 8; j++) {
        const float4* wyr = (const float4*)&wy[(o0 + j) * 32];
        const float4* wzr = (const float4*)&wz[(o0 + j) * 32];
        float ay = bt1[o0 + j];
        float az = wp[o0 + j] * pf;
#pragma unroll
        for (int c4 = 0; c4 < 8; c4++) {
            float4 a = wyr[c4], z = wzr[c4];
            ay = fmaf(a.x, v[4 * c4 + 0], ay);  az = fmaf(z.x, v[4 * c4 + 0], az);
            ay = fmaf(a.y, v[4 * c4 + 1], ay);  az = fmaf(z.y, v[4 * c4 + 1], az);
            ay = fmaf(a.z, v[4 * c4 + 2], ay);  az = fmaf(z.z, v[4 * c4 + 2], az);
            ay = fmaf(a.w, v[4 * c4 + 3], ay);  az = fmaf(z.w, v[4 * c4 + 3], az);
        }
        accY[j] = ay; accZ[j] = az;
    }

    float4* yp = (float4*)(wsYZ + (size_t)p * 32 + o0);
    float4* zp = (float4*)(wsYZ + ZOFS + (size_t)p * 32 + o0);
    yp[0] = make_float4(accY[0], accY[1], accY[2], accY[3]);
    yp[1] = make_float4(accY[4], accY[5], accY[6], accY[7]);
    zp[0] = make_float4(accZ[0], accZ[1], accZ[2], accZ[3]);
    zp[1] = make_float4(accZ[4], accZ[5], accZ[6], accZ[7]);
}

// ---- kernel B: MFMA MLP, LDS invariants (anti-LICM), 2-way chunk ILP -------
// r11 (pass, 115 us, occ 48%) was latency-bound on the serial chunk chain.
// This round: process TWO chunks per thread concurrently — every latency
// element gets 2 independent consumers; invariant LDS reads shared by the
// pair. Math identical to r10/r11 (absmax 0.0078).
__global__ __launch_bounds__(256) void main_kernel(
    const float* __restrict__ Pf, const float* __restrict__ Of,
    const int* __restrict__ args,
    const float* __restrict__ W1, const float* __restrict__ g1,
    const float* __restrict__ v1,
    const float* __restrict__ W2, const float* __restrict__ g2,
    const float* __restrict__ b2, const float* __restrict__ m2,
    const float* __restrict__ v2,
    const float* __restrict__ W3, const float* __restrict__ g3,
    const float* __restrict__ b3, const float* __restrict__ m3,
    const float* __restrict__ v3,
    const float* __restrict__ W4, const float* __restrict__ g4,
    const float* __restrict__ b4, const float* __restrict__ m4,
    const float* __restrict__ v4,
    const float* __restrict__ Wc, const float* __restrict__ bc,
    const float* __restrict__ ws, float* __restrict__ out)
{
    __shared__ __align__(16) unsigned wfrag[3][2][2][64][4]; // L,T,hi/lo,lane,pair
    __shared__ __align__(16) float btl[3 * 32];   // BN beta by [L][ch]
    __shared__ __align__(16) float wch[3 * 32];   // Wc rows A,B,O by ch
    __shared__ __align__(16) float w1t[2 * 32];   // W1 cols 65,66 folded, by ch
    __shared__ float bcs[3];
    __shared__ int   izs;

    const float* Ws[3] = {W2, W3, W4};
    const float* gs[3] = {g2, g3, g4};
    const float* vs[3] = {v2, v3, v4};
    const float* bs[3] = {b2, b3, b4};
    const float* ms[3] = {m2, m3, m4};

    for (int idx = threadIdx.x; idx < 1536; idx += 256) {
        int p    = idx & 3;
        int ln   = (idx >> 2) & 63;
        int T    = (idx >> 8) & 1;
        int L    = idx >> 9;
        int o    = T * 16 + (ln & 15);
        int c    = ((ln >> 4) << 3) + 2 * p;
        float inv = gs[L][o] * rsqrtf(vs[L][o] + 1e-5f);
        float w0 = Ws[L][o * 32 + c]     * inv;
        float w1 = Ws[L][o * 32 + c + 1] * inv;
        unsigned hi, lo;
        split_pack(w0, w1, hi, lo);
        wfrag[L][T][0][ln][p] = hi;
        wfrag[L][T][1][ln][p] = lo;
    }
    if (threadIdx.x < 96) {
        int L = threadIdx.x >> 5, ch = threadIdx.x & 31;
        btl[threadIdx.x] = bs[L][ch] - ms[L][ch] * (gs[L][ch] * rsqrtf(vs[L][ch] + 1e-5f));
        wch[threadIdx.x] = Wc[L * 32 + ch];
    }
    if (threadIdx.x < 64) {
        int t = threadIdx.x >> 5, ch = threadIdx.x & 31;
        float i1 = g1[ch] * rsqrtf(v1[ch] + 1e-5f);
        w1t[threadIdx.x] = W1[ch * 67 + 65 + t] * i1;
    }
    if (threadIdx.x < 3) bcs[threadIdx.x] = bc[threadIdx.x];
    if (threadIdx.x == 0) izs = (int)(args[0] >> 16);   // == 0, opaque
    __syncthreads();

    const int lane = threadIdx.x & 63;
    const int wid  = threadIdx.x >> 6;
    const int mI   = lane & 15;
    const int quad = lane >> 4;
    const int c0   = quad * 8;
    const int s0   = mI + 32 * (quad & 1);
    const int s1   = s0 + 16;
    const bool hiT = (quad >> 1) != 0;
    const int izero = izs;                              // 0, compiler-opaque

#pragma unroll 1
    for (int ii = 0; ii < 2; ii++) {
        const int io = ii & izero;                      // 0 every iter, unprovable

        // ---- front-load both chunks' global reads (args -> gathers) ----
        int bb_[2], nn_[2], aIdx[2];
        float of0v[2], of1v[2], pfg[2];
        f4 y0[2], y1[2], z0[2], z1[2];
#pragma unroll
        for (int u = 0; u < 2; u++) {
            const int C = blockIdx.x * 16 + wid * 4 + ii * 2 + u;
            const int b = (C >= NN) ? 1 : 0;
            const int n = C - b * NN;
            bb_[u] = b; nn_[u] = n;
            aIdx[u] = args[(b * NUMM + mI) * NN + n];
            of0v[u] = Of[((b * 2 + 0) * NUMM + mI) * NN + n];
            of1v[u] = Of[((b * 2 + 1) * NUMM + mI) * NN + n];
        }
#pragma unroll
        for (int u = 0; u < 2; u++) {
            pfg[u] = Pf[bb_[u] * NN + aIdx[u]];
            const f4* yp = (const f4*)(ws + (size_t)(bb_[u] * NN + nn_[u]) * 32 + c0);
            const f4* zp = (const f4*)(ws + ZOFS + (size_t)(bb_[u] * NN + aIdx[u]) * 32 + c0);
            y0[u] = yp[0]; y1[u] = yp[1]; z0[u] = zp[0]; z1[u] = zp[1];
        }

        // invariants (read once per pair; loop-variant addr via io)
        const f4 wo0a = *(const f4*)&w1t[c0 + 4 * io];
        const f4 wo0b = *(const f4*)&w1t[c0 + 4 + 4 * io];
        const f4 wo1a = *(const f4*)&w1t[32 + c0 + 4 * io];
        const f4 wo1b = *(const f4*)&w1t[32 + c0 + 4 + 4 * io];

        // ---- layer 1 ----
        UV Bv[2];
#pragma unroll
        for (int u = 0; u < 2; u++) {
            float x[8];
#pragma unroll
            for (int j = 0; j < 4; j++) {
                x[j]     = fmaf(of1v[u], wo1a[j], fmaf(of0v[u], wo0a[j], y0[u][j] + z0[u][j]));
                x[4 + j] = fmaf(of1v[u], wo1b[j], fmaf(of0v[u], wo0b[j], y1[u][j] + z1[u][j]));
            }
#pragma unroll
            for (int j = 0; j < 8; j++) x[j] = gelu_fast(x[j]);
#pragma unroll
            for (int p = 0; p < 4; p++) Bv[u].u[p] = pack2(x[2 * p], x[2 * p + 1]);
        }

        // ---- layer 2 ----
        f4 bt00 = *(const f4*)&btl[0 * 32 + 4 * quad + 4 * io];
        f4 bt01 = *(const f4*)&btl[0 * 32 + 16 + 4 * quad + 4 * io];
        short8 A0l = *(const short8*)&wfrag[0][0][1][lane + io][0];
        short8 A0h = *(const short8*)&wfrag[0][0][0][lane + io][0];
        short8 A1l = *(const short8*)&wfrag[0][1][1][lane + io][0];
        short8 A1h = *(const short8*)&wfrag[0][1][0][lane + io][0];
        f4 a0[2], a1[2];
        float h2c[2][8];
#pragma unroll
        for (int u = 0; u < 2; u++) {
            a0[u] = mm16(A0l, Bv[u].v, bt00);
            a0[u] = mm16(A0h, Bv[u].v, a0[u]);
            a1[u] = mm16(A1l, Bv[u].v, bt01);
            a1[u] = mm16(A1h, Bv[u].v, a1[u]);
        }
#pragma unroll
        for (int u = 0; u < 2; u++) {
#pragma unroll
            for (int r = 0; r < 4; r++) {
                h2c[u][r]     = gelu_fast(a0[u][r]);
                h2c[u][4 + r] = gelu_fast(a1[u][r]);
            }
            unsigned lo0 = pack2(h2c[u][0], h2c[u][1]), lo1 = pack2(h2c[u][2], h2c[u][3]);
            unsigned hi0 = pack2(h2c[u][4], h2c[u][5]), hi1 = pack2(h2c[u][6], h2c[u][7]);
            unsigned a0s0 = __shfl(lo0, s0, 64), b0s0 = __shfl(hi0, s0, 64);
            unsigned a1s0 = __shfl(lo1, s0, 64), b1s0 = __shfl(hi1, s0, 64);
            unsigned a0s1 = __shfl(lo0, s1, 64), b0s1 = __shfl(hi0, s1, 64);
            unsigned a1s1 = __shfl(lo1, s1, 64), b1s1 = __shfl(hi1, s1, 64);
            Bv[u].u[0] = hiT ? b0s0 : a0s0;
            Bv[u].u[1] = hiT ? b1s0 : a1s0;
            Bv[u].u[2] = hiT ? b0s1 : a0s1;
            Bv[u].u[3] = hiT ? b1s1 : a1s1;
        }

        // ---- layer 3 ----
        f4 bt10 = *(const f4*)&btl[1 * 32 + 4 * quad + 4 * io];
        f4 bt11 = *(const f4*)&btl[1 * 32 + 16 + 4 * quad + 4 * io];
        A0l = *(const short8*)&wfrag[1][0][1][lane + io][0];
        A0h = *(const short8*)&wfrag[1][0][0][lane + io][0];
        A1l = *(const short8*)&wfrag[1][1][1][lane + io][0];
        A1h = *(const short8*)&wfrag[1][1][0][lane + io][0];
#pragma unroll
        for (int u = 0; u < 2; u++) {
            a0[u] = mm16(A0l, Bv[u].v, bt10);
            a0[u] = mm16(A0h, Bv[u].v, a0[u]);
            a1[u] = mm16(A1l, Bv[u].v, bt11);
            a1[u] = mm16(A1h, Bv[u].v, a1[u]);
        }
#pragma unroll
        for (int u = 0; u < 2; u++) {
            float g0 = gelu_fast(a0[u][0]), g1_ = gelu_fast(a0[u][1]);
            float g2_ = gelu_fast(a0[u][2]), g3_ = gelu_fast(a0[u][3]);
            float g4_ = gelu_fast(a1[u][0]), g5 = gelu_fast(a1[u][1]);
            float g6 = gelu_fast(a1[u][2]), g7 = gelu_fast(a1[u][3]);
            unsigned lo0 = pack2(g0, g1_), lo1 = pack2(g2_, g3_);
            unsigned hi0 = pack2(g4_, g5), hi1 = pack2(g6, g7);
            unsigned a0s0 = __shfl(lo0, s0, 64), b0s0 = __shfl(hi0, s0, 64);
            unsigned a1s0 = __shfl(lo1, s0, 64), b1s0 = __shfl(hi1, s0, 64);
            unsigned a0s1 = __shfl(lo0, s1, 64), b0s1 = __shfl(hi0, s1, 64);
            unsigned a1s1 = __shfl(lo1, s1, 64), b1s1 = __shfl(hi1, s1, 64);
            Bv[u].u[0] = hiT ? b0s0 : a0s0;
            Bv[u].u[1] = hiT ? b1s0 : a1s0;
            Bv[u].u[2] = hiT ? b0s1 : a0s1;
            Bv[u].u[3] = hiT ? b1s1 : a1s1;
        }

        // ---- layer 4 + residual + head ----
        f4 bt20 = *(const f4*)&btl[2 * 32 + 4 * quad + 4 * io];
        f4 bt21 = *(const f4*)&btl[2 * 32 + 16 + 4 * quad + 4 * io];
        A0l = *(const short8*)&wfrag[2][0][1][lane + io][0];
        A0h = *(const short8*)&wfrag[2][0][0][lane + io][0];
        A1l = *(const short8*)&wfrag[2][1][1][lane + io][0];
        A1h = *(const short8*)&wfrag[2][1][0][lane + io][0];
#pragma unroll
        for (int u = 0; u < 2; u++) {
            a0[u] = mm16(A0l, Bv[u].v, bt20);
            a0[u] = mm16(A0h, Bv[u].v, a0[u]);
            a1[u] = mm16(A1l, Bv[u].v, bt21);
            a1[u] = mm16(A1h, Bv[u].v, a1[u]);
        }

        const f4 wA0 = *(const f4*)&wch[0 * 32 + 4 * quad + 4 * io];
        const f4 wA1 = *(const f4*)&wch[0 * 32 + 16 + 4 * quad + 4 * io];
        const f4 wB0 = *(const f4*)&wch[1 * 32 + 4 * quad + 4 * io];
        const f4 wB1 = *(const f4*)&wch[1 * 32 + 16 + 4 * quad + 4 * io];
        const f4 wO0 = *(const f4*)&wch[2 * 32 + 4 * quad + 4 * io];
        const f4 wO1 = *(const f4*)&wch[2 * 32 + 16 + 4 * quad + 4 * io];
        const float bc0 = bcs[0], bc1 = bcs[1], bc2 = bcs[2];

#pragma unroll
        for (int u = 0; u < 2; u++) {
            float pa = 0.0f, pb = 0.0f, po = 0.0f;
#pragma unroll
            for (int r = 0; r < 4; r++) {
                float xf0 = gelu_fast(h2c[u][r]     + a0[u][r]);
                float xf1 = gelu_fast(h2c[u][4 + r] + a1[u][r]);
                pa = fmaf(wA0[r], xf0, pa);  pa = fmaf(wA1[r], xf1, pa);
                pb = fmaf(wB0[r], xf0, pb);  pb = fmaf(wB1[r], xf1, pb);
                po = fmaf(wO0[r], xf0, po);  po = fmaf(wO1[r], xf1, po);
            }
            pa += __shfl_xor(pa, 16, 64);  pa += __shfl_xor(pa, 32, 64);
            pb += __shfl_xor(pb, 16, 64);  pb += __shfl_xor(pb, 32, 64);
            po += __shfl_xor(po, 16, 64);  po += __shfl_xor(po, 32, 64);
            const float alpha = pa + bc0;
            const float beta_ = pb + bc1;
            const float omega = po + bc2;
            const float val = fmaf(alpha + 1.0f, pfg[u], beta_);

            float mx = omega;
#pragma unroll
            for (int s = 1; s < 16; s <<= 1) mx = fmaxf(mx, __shfl_xor(mx, s, 64));
            const float e = __expf(omega - mx);
            float S = e, T = val * e;
#pragma unroll
            for (int s = 1; s < 16; s <<= 1) {
                S += __shfl_xor(S, s, 64);
                T += __shfl_xor(T, s, 64);
            }
            if (lane == 0) out[bb_[u] * NN + nn_[u]] = T / S;
        }
    }
}

// ---- launcher ---------------------------------------------------------------
extern "C" void kernel_launch(void* const* d_in, const int* in_sizes, int n_in,
                              void* d_out, int out_size, void* d_ws, size_t ws_size,
                              hipStream_t stream) {
    const float* If    = (const float*)d_in[0];
    const float* Pf    = (const float*)d_in[1];
    const float* Of    = (const float*)d_in[2];
    const int*   args  = (const int*)d_in[3];
    const float* W1    = (const float*)d_in[4];
    const float* g1    = (const float*)d_in[5];
    const float* b1    = (const float*)d_in[6];
    const float* m1    = (const float*)d_in[7];
    const float* v1    = (const float*)d_in[8];
    const float* W2    = (const float*)d_in[9];
    const float* g2    = (const float*)d_in[10];
    const float* b2    = (const float*)d_in[11];
    const float* m2    = (const float*)d_in[12];
    const float* v2    = (const float*)d_in[13];
    const float* W3    = (const float*)d_in[14];
    const float* g3    = (const float*)d_in[15];
    const float* b3    = (const float*)d_in[16];
    const float* m3    = (const float*)d_in[17];
    const float* v3    = (const float*)d_in[18];
    const float* W4    = (const float*)d_in[19];
    const float* g4    = (const float*)d_in[20];
    const float* b4    = (const float*)d_in[21];
    const float* m4    = (const float*)d_in[22];
    const float* v4    = (const float*)d_in[23];
    const float* Wc    = (const float*)d_in[24];
    const float* bc    = (const float*)d_in[25];

    float* ws  = (float*)d_ws;
    float* out = (float*)d_out;

    yz_kernel<<<(BB * NN) / 64, 256, 0, stream>>>(
        If, Pf, W1, g1, b1, m1, v1, ws);

    main_kernel<<<(BB * NN) / 16, 256, 0, stream>>>(
        Pf, Of, args,
        W1, g1, v1,
        W2, g2, b2, m2, v2,
        W3, g3, b3, m3, v3,
        W4, g4, b4, m4, v4,
        Wc, bc, ws, out);
}

// Round 13
// 236.918 us; speedup vs baseline: 1.0423x; 1.0423x over previous
//
#include <hip/hip_runtime.h>
#include <math.h>

#define BB   2
#define CFI  32
#define NN   36864          // 192*192
#define NUMM 16

// workspace: Y at ws[0..], Z at ws[ZOFS..]  (point-major [B*N][32] each)
#define ZOFS (BB * NN * CFI)

typedef __attribute__((ext_vector_type(8))) short short8;   // 8 bf16 (4 VGPRs)
typedef __attribute__((ext_vector_type(4))) float f4;       // 4 f32

static __device__ __forceinline__ f4 mm16(short8 a, short8 b, f4 c) {
    return __builtin_amdgcn_mfma_f32_16x16x32_bf16(a, b, c, 0, 0, 0);
}

// tanh-form gelu: x * sigmoid(1.595769x + 0.0713548x^3), exp2-folded.
static __device__ __forceinline__ float gelu_fast(float x) {
    const float x2  = x * x;
    const float q   = fmaf(-0.10294310f, x2, -2.30211813f);
    const float e   = exp2f(q * x);
    const float r   = __builtin_amdgcn_rcpf(e + 1.0f);
    return x * r;
}

static __device__ __forceinline__ unsigned bf16_rne_bits(float x) {
    unsigned u = __builtin_bit_cast(unsigned, x);
    return u + 0x7fffu + ((u >> 16) & 1u);
}
static __device__ __forceinline__ void split_pack(float x0, float x1,
                                                  unsigned& hi, unsigned& lo) {
    unsigned r0 = bf16_rne_bits(x0);
    unsigned r1 = bf16_rne_bits(x1);
    float h0 = __builtin_bit_cast(float, r0 & 0xffff0000u);
    float h1 = __builtin_bit_cast(float, r1 & 0xffff0000u);
    hi = (r0 >> 16) | (r1 & 0xffff0000u);
    unsigned s0 = bf16_rne_bits(x0 - h0);
    unsigned s1 = bf16_rne_bits(x1 - h1);
    lo = (s0 >> 16) | (s1 & 0xffff0000u);
}

// cheap round-half-up bf16 pair pack (activations)
static __device__ __forceinline__ unsigned pack2(float a, float b) {
    unsigned ua = __builtin_bit_cast(unsigned, a) + 0x8000u;
    unsigned ub = __builtin_bit_cast(unsigned, b) + 0x8000u;
    return (ua >> 16) | (ub & 0xffff0000u);
}

union UV { unsigned u[4]; short8 v; };

// ---- kernel A: per-point Y/Z precompute (layer-1 split) -- unchanged ------
__global__ __launch_bounds__(256) void yz_kernel(
    const float* __restrict__ If, const float* __restrict__ Pf,
    const float* __restrict__ W1, const float* __restrict__ g1,
    const float* __restrict__ b1, const float* __restrict__ m1,
    const float* __restrict__ v1,
    float* __restrict__ wsYZ)
{
    __shared__ float wy[1024], wz[1024], wp[32], bt1[32];
    for (int i = threadIdx.x; i < 1024; i += 256) {
        int o = i >> 5, c = i & 31;
        float inv = g1[o] * rsqrtf(v1[o] + 1e-5f);
        wy[i] = W1[o * 67 + c]      * inv;
        wz[i] = W1[o * 67 + 32 + c] * inv;
    }
    if (threadIdx.x < 32) {
        int o = threadIdx.x;
        float inv = g1[o] * rsqrtf(v1[o] + 1e-5f);
        wp[o]  = W1[o * 67 + 64] * inv;
        bt1[o] = b1[o] - m1[o] * inv;
    }
    __syncthreads();

    const int r  = threadIdx.x & 3;
    const int p  = blockIdx.x * 64 + (threadIdx.x >> 2);
    const int b  = p / NN, n = p - b * NN;
    const int o0 = r * 8;
    const float* ifp = If + (size_t)b * CFI * NN + n;

    float v[32];
#pragma unroll
    for (int c = 0; c < 32; c++) v[c] = ifp[(size_t)c * NN];
    const float pf = Pf[p];

    float accY[8], accZ[8];
#pragma unroll
    for (int j = 0; j < 8; j++) {
        const float4* wyr = (const float4*)&wy[(o0 + j) * 32];
        const float4* wzr = (const float4*)&wz[(o0 + j) * 32];
        float ay = bt1[o0 + j];
        float az = wp[o0 + j] * pf;
#pragma unroll
        for (int c4 = 0; c4 < 8; c4++) {
            float4 a = wyr[c4], z = wzr[c4];
            ay = fmaf(a.x, v[4 * c4 + 0], ay);  az = fmaf(z.x, v[4 * c4 + 0], az);
            ay = fmaf(a.y, v[4 * c4 + 1], ay);  az = fmaf(z.y, v[4 * c4 + 1], az);
            ay = fmaf(a.z, v[4 * c4 + 2], ay);  az = fmaf(z.z, v[4 * c4 + 2], az);
            ay = fmaf(a.w, v[4 * c4 + 3], ay);  az = fmaf(z.w, v[4 * c4 + 3], az);
        }
        accY[j] = ay; accZ[j] = az;
    }

    float4* yp = (float4*)(wsYZ + (size_t)p * 32 + o0);
    float4* zp = (float4*)(wsYZ + ZOFS + (size_t)p * 32 + o0);
    yp[0] = make_float4(accY[0], accY[1], accY[2], accY[3]);
    yp[1] = make_float4(accY[4], accY[5], accY[6], accY[7]);
    zp[0] = make_float4(accZ[0], accZ[1], accZ[2], accZ[3]);
    zp[1] = make_float4(accZ[4], accZ[5], accZ[6], accZ[7]);
}

// ---- kernel B: MFMA MLP, LDS invariants (anti-LICM), single-chunk ---------
// Identical math/structure to round 11 (115 us, occ 48%). One change:
// __launch_bounds__(256, 6) forces the unified VGPR+AGPR budget to ~85/wave
// so the allocator cannot park hidden invariants in AGPRs (r11 evidence:
// VGPR_Count 44 but occupancy 48% => ~90 hidden AGPRs/wave). Target 6
// waves/SIMD for latency hiding on the serial chunk chain.
__global__ __launch_bounds__(256, 6) void main_kernel(
    const float* __restrict__ Pf, const float* __restrict__ Of,
    const int* __restrict__ args,
    const float* __restrict__ W1, const float* __restrict__ g1,
    const float* __restrict__ v1,
    const float* __restrict__ W2, const float* __restrict__ g2,
    const float* __restrict__ b2, const float* __restrict__ m2,
    const float* __restrict__ v2,
    const float* __restrict__ W3, const float* __restrict__ g3,
    const float* __restrict__ b3, const float* __restrict__ m3,
    const float* __restrict__ v3,
    const float* __restrict__ W4, const float* __restrict__ g4,
    const float* __restrict__ b4, const float* __restrict__ m4,
    const float* __restrict__ v4,
    const float* __restrict__ Wc, const float* __restrict__ bc,
    const float* __restrict__ ws, float* __restrict__ out)
{
    __shared__ __align__(16) unsigned wfrag[3][2][2][64][4]; // L,T,hi/lo,lane,pair
    __shared__ __align__(16) float btl[3 * 32];   // BN beta by [L][ch]
    __shared__ __align__(16) float wch[3 * 32];   // Wc rows A,B,O by ch
    __shared__ __align__(16) float w1t[2 * 32];   // W1 cols 65,66 folded, by ch
    __shared__ float bcs[3];
    __shared__ int   izs;

    const float* Ws[3] = {W2, W3, W4};
    const float* gs[3] = {g2, g3, g4};
    const float* vs[3] = {v2, v3, v4};
    const float* bs[3] = {b2, b3, b4};
    const float* ms[3] = {m2, m3, m4};

    for (int idx = threadIdx.x; idx < 1536; idx += 256) {
        int p    = idx & 3;
        int ln   = (idx >> 2) & 63;
        int T    = (idx >> 8) & 1;
        int L    = idx >> 9;
        int o    = T * 16 + (ln & 15);
        int c    = ((ln >> 4) << 3) + 2 * p;
        float inv = gs[L][o] * rsqrtf(vs[L][o] + 1e-5f);
        float w0 = Ws[L][o * 32 + c]     * inv;
        float w1 = Ws[L][o * 32 + c + 1] * inv;
        unsigned hi, lo;
        split_pack(w0, w1, hi, lo);
        wfrag[L][T][0][ln][p] = hi;
        wfrag[L][T][1][ln][p] = lo;
    }
    if (threadIdx.x < 96) {
        int L = threadIdx.x >> 5, ch = threadIdx.x & 31;
        btl[threadIdx.x] = bs[L][ch] - ms[L][ch] * (gs[L][ch] * rsqrtf(vs[L][ch] + 1e-5f));
        wch[threadIdx.x] = Wc[L * 32 + ch];
    }
    if (threadIdx.x < 64) {
        int t = threadIdx.x >> 5, ch = threadIdx.x & 31;
        float i1 = g1[ch] * rsqrtf(v1[ch] + 1e-5f);
        w1t[threadIdx.x] = W1[ch * 67 + 65 + t] * i1;
    }
    if (threadIdx.x < 3) bcs[threadIdx.x] = bc[threadIdx.x];
    if (threadIdx.x == 0) izs = (int)(args[0] >> 16);   // == 0, opaque
    __syncthreads();

    const int lane = threadIdx.x & 63;
    const int wid  = threadIdx.x >> 6;
    const int mI   = lane & 15;
    const int quad = lane >> 4;
    const int c0   = quad * 8;
    const int s0   = mI + 32 * (quad & 1);
    const int s1   = s0 + 16;
    const bool hiT = (quad >> 1) != 0;
    const int izero = izs;                              // 0, compiler-opaque

#pragma unroll 1
    for (int i = 0; i < 4; i++) {
        const int io  = i & izero;                      // 0 every iter, unprovable
        const int C = blockIdx.x * 16 + wid * 4 + i;    // 0 .. B*NN-1
        const int b = (C >= NN) ? 1 : 0;
        const int n = C - b * NN;

        const int   aIdx = args[(b * NUMM + mI) * NN + n];
        const float of0v = Of[((b * 2 + 0) * NUMM + mI) * NN + n];
        const float of1v = Of[((b * 2 + 1) * NUMM + mI) * NN + n];
        const float pfg  = Pf[b * NN + aIdx];

        const f4* yp = (const f4*)(ws + (size_t)(b * NN + n) * 32 + c0);
        const f4* zp = (const f4*)(ws + ZOFS + (size_t)(b * NN + aIdx) * 32 + c0);
        f4 y0 = yp[0], y1 = yp[1], z0 = zp[0], z1 = zp[1];

        // invariant reads (loop-variant addresses via io -> stay in loop)
        const f4 wo0a = *(const f4*)&w1t[c0 + 4 * io];
        const f4 wo0b = *(const f4*)&w1t[c0 + 4 + 4 * io];
        const f4 wo1a = *(const f4*)&w1t[32 + c0 + 4 * io];
        const f4 wo1b = *(const f4*)&w1t[32 + c0 + 4 + 4 * io];

        // ---- layer 1: h1 = gelu(Y+Z+of terms) -> directly the B fragment ----
        float x[8];
#pragma unroll
        for (int j = 0; j < 4; j++) {
            x[j]     = fmaf(of1v, wo1a[j], fmaf(of0v, wo0a[j], y0[j] + z0[j]));
            x[4 + j] = fmaf(of1v, wo1b[j], fmaf(of0v, wo0b[j], y1[j] + z1[j]));
        }
#pragma unroll
        for (int j = 0; j < 8; j++) x[j] = gelu_fast(x[j]);
        UV Bv;
#pragma unroll
        for (int p = 0; p < 4; p++) Bv.u[p] = pack2(x[2 * p], x[2 * p + 1]);

        // ---- layer 2 ----
        f4 bt00 = *(const f4*)&btl[0 * 32 + 4 * quad + 4 * io];
        f4 bt01 = *(const f4*)&btl[0 * 32 + 16 + 4 * quad + 4 * io];
        short8 A0l = *(const short8*)&wfrag[0][0][1][lane + io][0];
        short8 A0h = *(const short8*)&wfrag[0][0][0][lane + io][0];
        short8 A1l = *(const short8*)&wfrag[0][1][1][lane + io][0];
        short8 A1h = *(const short8*)&wfrag[0][1][0][lane + io][0];
        f4 acc0 = mm16(A0l, Bv.v, bt00);
        acc0    = mm16(A0h, Bv.v, acc0);
        f4 acc1 = mm16(A1l, Bv.v, bt01);
        acc1    = mm16(A1h, Bv.v, acc1);
        float h2c[8];
#pragma unroll
        for (int r = 0; r < 4; r++) {
            h2c[r]     = gelu_fast(acc0[r]);
            h2c[4 + r] = gelu_fast(acc1[r]);
        }
        // C -> B: publish both tiles, select by target hiT after the shuffle
        {
            unsigned lo0 = pack2(h2c[0], h2c[1]), lo1 = pack2(h2c[2], h2c[3]);
            unsigned hi0 = pack2(h2c[4], h2c[5]), hi1 = pack2(h2c[6], h2c[7]);
            unsigned a0s0 = __shfl(lo0, s0, 64), b0s0 = __shfl(hi0, s0, 64);
            unsigned a1s0 = __shfl(lo1, s0, 64), b1s0 = __shfl(hi1, s0, 64);
            unsigned a0s1 = __shfl(lo0, s1, 64), b0s1 = __shfl(hi0, s1, 64);
            unsigned a1s1 = __shfl(lo1, s1, 64), b1s1 = __shfl(hi1, s1, 64);
            Bv.u[0] = hiT ? b0s0 : a0s0;
            Bv.u[1] = hiT ? b1s0 : a1s0;
            Bv.u[2] = hiT ? b0s1 : a0s1;
            Bv.u[3] = hiT ? b1s1 : a1s1;
        }

        // ---- layer 3 ----
        f4 bt10 = *(const f4*)&btl[1 * 32 + 4 * quad + 4 * io];
        f4 bt11 = *(const f4*)&btl[1 * 32 + 16 + 4 * quad + 4 * io];
        A0l = *(const short8*)&wfrag[1][0][1][lane + io][0];
        A0h = *(const short8*)&wfrag[1][0][0][lane + io][0];
        A1l = *(const short8*)&wfrag[1][1][1][lane + io][0];
        A1h = *(const short8*)&wfrag[1][1][0][lane + io][0];
        acc0 = mm16(A0l, Bv.v, bt10);
        acc0 = mm16(A0h, Bv.v, acc0);
        acc1 = mm16(A1l, Bv.v, bt11);
        acc1 = mm16(A1h, Bv.v, acc1);
        {
            float g0 = gelu_fast(acc0[0]), g1_ = gelu_fast(acc0[1]);
            float g2_ = gelu_fast(acc0[2]), g3_ = gelu_fast(acc0[3]);
            float g4_ = gelu_fast(acc1[0]), g5 = gelu_fast(acc1[1]);
            float g6 = gelu_fast(acc1[2]), g7 = gelu_fast(acc1[3]);
            unsigned lo0 = pack2(g0, g1_), lo1 = pack2(g2_, g3_);
            unsigned hi0 = pack2(g4_, g5), hi1 = pack2(g6, g7);
            unsigned a0s0 = __shfl(lo0, s0, 64), b0s0 = __shfl(hi0, s0, 64);
            unsigned a1s0 = __shfl(lo1, s0, 64), b1s0 = __shfl(hi1, s0, 64);
            unsigned a0s1 = __shfl(lo0, s1, 64), b0s1 = __shfl(hi0, s1, 64);
            unsigned a1s1 = __shfl(lo1, s1, 64), b1s1 = __shfl(hi1, s1, 64);
            Bv.u[0] = hiT ? b0s0 : a0s0;
            Bv.u[1] = hiT ? b1s0 : a1s0;
            Bv.u[2] = hiT ? b0s1 : a0s1;
            Bv.u[3] = hiT ? b1s1 : a1s1;
        }

        // ---- layer 4 + residual + head (all in C layout) ----
        f4 bt20 = *(const f4*)&btl[2 * 32 + 4 * quad + 4 * io];
        f4 bt21 = *(const f4*)&btl[2 * 32 + 16 + 4 * quad + 4 * io];
        A0l = *(const short8*)&wfrag[2][0][1][lane + io][0];
        A0h = *(const short8*)&wfrag[2][0][0][lane + io][0];
        A1l = *(const short8*)&wfrag[2][1][1][lane + io][0];
        A1h = *(const short8*)&wfrag[2][1][0][lane + io][0];
        acc0 = mm16(A0l, Bv.v, bt20);
        acc0 = mm16(A0h, Bv.v, acc0);
        acc1 = mm16(A1l, Bv.v, bt21);
        acc1 = mm16(A1h, Bv.v, acc1);

        const f4 wA0 = *(const f4*)&wch[0 * 32 + 4 * quad + 4 * io];
        const f4 wA1 = *(const f4*)&wch[0 * 32 + 16 + 4 * quad + 4 * io];
        const f4 wB0 = *(const f4*)&wch[1 * 32 + 4 * quad + 4 * io];
        const f4 wB1 = *(const f4*)&wch[1 * 32 + 16 + 4 * quad + 4 * io];
        const f4 wO0 = *(const f4*)&wch[2 * 32 + 4 * quad + 4 * io];
        const f4 wO1 = *(const f4*)&wch[2 * 32 + 16 + 4 * quad + 4 * io];

        float pa = 0.0f, pb = 0.0f, po = 0.0f;
#pragma unroll
        for (int r = 0; r < 4; r++) {
            float xf0 = gelu_fast(h2c[r]     + acc0[r]);
            float xf1 = gelu_fast(h2c[4 + r] + acc1[r]);
            pa = fmaf(wA0[r], xf0, pa);  pa = fmaf(wA1[r], xf1, pa);
            pb = fmaf(wB0[r], xf0, pb);  pb = fmaf(wB1[r], xf1, pb);
            po = fmaf(wO0[r], xf0, po);  po = fmaf(wO1[r], xf1, po);
        }
        pa += __shfl_xor(pa, 16, 64);  pa += __shfl_xor(pa, 32, 64);
        pb += __shfl_xor(pb, 16, 64);  pb += __shfl_xor(pb, 32, 64);
        po += __shfl_xor(po, 16, 64);  po += __shfl_xor(po, 32, 64);
        const float alpha = pa + bcs[0];
        const float beta_ = pb + bcs[1];
        const float omega = po + bcs[2];
        const float val = fmaf(alpha + 1.0f, pfg, beta_);

        // softmax over the 16 m's
        float mx = omega;
#pragma unroll
        for (int s = 1; s < 16; s <<= 1) mx = fmaxf(mx, __shfl_xor(mx, s, 64));
        const float e = __expf(omega - mx);
        float S = e, T = val * e;
#pragma unroll
        for (int s = 1; s < 16; s <<= 1) {
            S += __shfl_xor(S, s, 64);
            T += __shfl_xor(T, s, 64);
        }
        if (lane == 0) out[b * NN + n] = T / S;
    }
}

// ---- launcher ---------------------------------------------------------------
extern "C" void kernel_launch(void* const* d_in, const int* in_sizes, int n_in,
                              void* d_out, int out_size, void* d_ws, size_t ws_size,
                              hipStream_t stream) {
    const float* If    = (const float*)d_in[0];
    const float* Pf    = (const float*)d_in[1];
    const float* Of    = (const float*)d_in[2];
    const int*   args  = (const int*)d_in[3];
    const float* W1    = (const float*)d_in[4];
    const float* g1    = (const float*)d_in[5];
    const float* b1    = (const float*)d_in[6];
    const float* m1    = (const float*)d_in[7];
    const float* v1    = (const float*)d_in[8];
    const float* W2    = (const float*)d_in[9];
    const float* g2    = (const float*)d_in[10];
    const float* b2    = (const float*)d_in[11];
    const float* m2    = (const float*)d_in[12];
    const float* v2    = (const float*)d_in[13];
    const float* W3    = (const float*)d_in[14];
    const float* g3    = (const float*)d_in[15];
    const float* b3    = (const float*)d_in[16];
    const float* m3    = (const float*)d_in[17];
    const float* v3    = (const float*)d_in[18];
    const float* W4    = (const float*)d_in[19];
    const float* g4    = (const float*)d_in[20];
    const float* b4    = (const float*)d_in[21];
    const float* m4    = (const float*)d_in[22];
    const float* v4    = (const float*)d_in[23];
    const float* Wc    = (const float*)d_in[24];
    const float* bc    = (const float*)d_in[25];

    float* ws  = (float*)d_ws;
    float* out = (float*)d_out;

    yz_kernel<<<(BB * NN) / 64, 256, 0, stream>>>(
        If, Pf, W1, g1, b1, m1, v1, ws);

    main_kernel<<<(BB * NN) / 16, 256, 0, stream>>>(
        Pf, Of, args,
        W1, g1, v1,
        W2, g2, b2, m2, v2,
        W3, g3, b3, m3, v3,
        W4, g4, b4, m4, v4,
        Wc, bc, ws, out);
}

// Round 14
// 229.491 us; speedup vs baseline: 1.0760x; 1.0324x over previous
//
#include <hip/hip_runtime.h>
#include <math.h>

#define BB   2
#define CFI  32
#define NN   36864          // 192*192
#define NUMM 16

// workspace: Y at ws[0..], Z at ws[ZOFS..]  (point-major [B*N][32] each)
#define ZOFS (BB * NN * CFI)

typedef __attribute__((ext_vector_type(8))) short short8;   // 8 bf16 (4 VGPRs)
typedef __attribute__((ext_vector_type(4))) float f4;       // 4 f32

static __device__ __forceinline__ f4 mm16(short8 a, short8 b, f4 c) {
    return __builtin_amdgcn_mfma_f32_16x16x32_bf16(a, b, c, 0, 0, 0);
}

// tanh-form gelu: x * sigmoid(1.595769x + 0.0713548x^3), exp2-folded.
static __device__ __forceinline__ float gelu_fast(float x) {
    const float x2  = x * x;
    const float q   = fmaf(-0.10294310f, x2, -2.30211813f);
    const float e   = exp2f(q * x);
    const float r   = __builtin_amdgcn_rcpf(e + 1.0f);
    return x * r;
}

static __device__ __forceinline__ unsigned bf16_rne_bits(float x) {
    unsigned u = __builtin_bit_cast(unsigned, x);
    return u + 0x7fffu + ((u >> 16) & 1u);
}
static __device__ __forceinline__ void split_pack(float x0, float x1,
                                                  unsigned& hi, unsigned& lo) {
    unsigned r0 = bf16_rne_bits(x0);
    unsigned r1 = bf16_rne_bits(x1);
    float h0 = __builtin_bit_cast(float, r0 & 0xffff0000u);
    float h1 = __builtin_bit_cast(float, r1 & 0xffff0000u);
    hi = (r0 >> 16) | (r1 & 0xffff0000u);
    unsigned s0 = bf16_rne_bits(x0 - h0);
    unsigned s1 = bf16_rne_bits(x1 - h1);
    lo = (s0 >> 16) | (s1 & 0xffff0000u);
}

// cheap round-half-up bf16 pair pack (activations)
static __device__ __forceinline__ unsigned pack2(float a, float b) {
    unsigned ua = __builtin_bit_cast(unsigned, a) + 0x8000u;
    unsigned ub = __builtin_bit_cast(unsigned, b) + 0x8000u;
    return (ua >> 16) | (ub & 0xffff0000u);
}

union UV { unsigned u[4]; short8 v; };

// ---- kernel A: per-point Y/Z precompute (layer-1 split) -- unchanged ------
__global__ __launch_bounds__(256) void yz_kernel(
    const float* __restrict__ If, const float* __restrict__ Pf,
    const float* __restrict__ W1, const float* __restrict__ g1,
    const float* __restrict__ b1, const float* __restrict__ m1,
    const float* __restrict__ v1,
    float* __restrict__ wsYZ)
{
    __shared__ float wy[1024], wz[1024], wp[32], bt1[32];
    for (int i = threadIdx.x; i < 1024; i += 256) {
        int o = i >> 5, c = i & 31;
        float inv = g1[o] * rsqrtf(v1[o] + 1e-5f);
        wy[i] = W1[o * 67 + c]      * inv;
        wz[i] = W1[o * 67 + 32 + c] * inv;
    }
    if (threadIdx.x < 32) {
        int o = threadIdx.x;
        float inv = g1[o] * rsqrtf(v1[o] + 1e-5f);
        wp[o]  = W1[o * 67 + 64] * inv;
        bt1[o] = b1[o] - m1[o] * inv;
    }
    __syncthreads();

    const int r  = threadIdx.x & 3;
    const int p  = blockIdx.x * 64 + (threadIdx.x >> 2);
    const int b  = p / NN, n = p - b * NN;
    const int o0 = r * 8;
    const float* ifp = If + (size_t)b * CFI * NN + n;

    float v[32];
#pragma unroll
    for (int c = 0; c < 32; c++) v[c] = ifp[(size_t)c * NN];
    const float pf = Pf[p];

    float accY[8], accZ[8];
#pragma unroll
    for (int j = 0; j < 8; j++) {
        const float4* wyr = (const float4*)&wy[(o0 + j) * 32];
        const float4* wzr = (const float4*)&wz[(o0 + j) * 32];
        float ay = bt1[o0 + j];
        float az = wp[o0 + j] * pf;
#pragma unroll
        for (int c4 = 0; c4 < 8; c4++) {
            float4 a = wyr[c4], z = wzr[c4];
            ay = fmaf(a.x, v[4 * c4 + 0], ay);  az = fmaf(z.x, v[4 * c4 + 0], az);
            ay = fmaf(a.y, v[4 * c4 + 1], ay);  az = fmaf(z.y, v[4 * c4 + 1], az);
            ay = fmaf(a.z, v[4 * c4 + 2], ay);  az = fmaf(z.z, v[4 * c4 + 2], az);
            ay = fmaf(a.w, v[4 * c4 + 3], ay);  az = fmaf(z.w, v[4 * c4 + 3], az);
        }
        accY[j] = ay; accZ[j] = az;
    }

    float4* yp = (float4*)(wsYZ + (size_t)p * 32 + o0);
    float4* zp = (float4*)(wsYZ + ZOFS + (size_t)p * 32 + o0);
    yp[0] = make_float4(accY[0], accY[1], accY[2], accY[3]);
    yp[1] = make_float4(accY[4], accY[5], accY[6], accY[7]);
    zp[0] = make_float4(accZ[0], accZ[1], accZ[2], accZ[3]);
    zp[1] = make_float4(accZ[4], accZ[5], accZ[6], accZ[7]);
}

// ---- kernel B: MFMA MLP, LDS invariants (anti-LICM), single-chunk ---------
// r13: __launch_bounds__(256,6) -> occ 71% but 85-reg budget forced scratch
// spills (WRITE_SIZE 0.3 -> 55.7 MB), netting only 115 -> 108 us. Working
// set is ~90-100 regs. This round: (256,5) -> ~102-reg budget — keep most
// of the occupancy, eliminate the spill.
__global__ __launch_bounds__(256, 5) void main_kernel(
    const float* __restrict__ Pf, const float* __restrict__ Of,
    const int* __restrict__ args,
    const float* __restrict__ W1, const float* __restrict__ g1,
    const float* __restrict__ v1,
    const float* __restrict__ W2, const float* __restrict__ g2,
    const float* __restrict__ b2, const float* __restrict__ m2,
    const float* __restrict__ v2,
    const float* __restrict__ W3, const float* __restrict__ g3,
    const float* __restrict__ b3, const float* __restrict__ m3,
    const float* __restrict__ v3,
    const float* __restrict__ W4, const float* __restrict__ g4,
    const float* __restrict__ b4, const float* __restrict__ m4,
    const float* __restrict__ v4,
    const float* __restrict__ Wc, const float* __restrict__ bc,
    const float* __restrict__ ws, float* __restrict__ out)
{
    __shared__ __align__(16) unsigned wfrag[3][2][2][64][4]; // L,T,hi/lo,lane,pair
    __shared__ __align__(16) float btl[3 * 32];   // BN beta by [L][ch]
    __shared__ __align__(16) float wch[3 * 32];   // Wc rows A,B,O by ch
    __shared__ __align__(16) float w1t[2 * 32];   // W1 cols 65,66 folded, by ch
    __shared__ float bcs[3];
    __shared__ int   izs;

    const float* Ws[3] = {W2, W3, W4};
    const float* gs[3] = {g2, g3, g4};
    const float* vs[3] = {v2, v3, v4};
    const float* bs[3] = {b2, b3, b4};
    const float* ms[3] = {m2, m3, m4};

    for (int idx = threadIdx.x; idx < 1536; idx += 256) {
        int p    = idx & 3;
        int ln   = (idx >> 2) & 63;
        int T    = (idx >> 8) & 1;
        int L    = idx >> 9;
        int o    = T * 16 + (ln & 15);
        int c    = ((ln >> 4) << 3) + 2 * p;
        float inv = gs[L][o] * rsqrtf(vs[L][o] + 1e-5f);
        float w0 = Ws[L][o * 32 + c]     * inv;
        float w1 = Ws[L][o * 32 + c + 1] * inv;
        unsigned hi, lo;
        split_pack(w0, w1, hi, lo);
        wfrag[L][T][0][ln][p] = hi;
        wfrag[L][T][1][ln][p] = lo;
    }
    if (threadIdx.x < 96) {
        int L = threadIdx.x >> 5, ch = threadIdx.x & 31;
        btl[threadIdx.x] = bs[L][ch] - ms[L][ch] * (gs[L][ch] * rsqrtf(vs[L][ch] + 1e-5f));
        wch[threadIdx.x] = Wc[L * 32 + ch];
    }
    if (threadIdx.x < 64) {
        int t = threadIdx.x >> 5, ch = threadIdx.x & 31;
        float i1 = g1[ch] * rsqrtf(v1[ch] + 1e-5f);
        w1t[threadIdx.x] = W1[ch * 67 + 65 + t] * i1;
    }
    if (threadIdx.x < 3) bcs[threadIdx.x] = bc[threadIdx.x];
    if (threadIdx.x == 0) izs = (int)(args[0] >> 16);   // == 0, opaque
    __syncthreads();

    const int lane = threadIdx.x & 63;
    const int wid  = threadIdx.x >> 6;
    const int mI   = lane & 15;
    const int quad = lane >> 4;
    const int c0   = quad * 8;
    const int s0   = mI + 32 * (quad & 1);
    const int s1   = s0 + 16;
    const bool hiT = (quad >> 1) != 0;
    const int izero = izs;                              // 0, compiler-opaque

#pragma unroll 1
    for (int i = 0; i < 4; i++) {
        const int io  = i & izero;                      // 0 every iter, unprovable
        const int C = blockIdx.x * 16 + wid * 4 + i;    // 0 .. B*NN-1
        const int b = (C >= NN) ? 1 : 0;
        const int n = C - b * NN;

        const int   aIdx = args[(b * NUMM + mI) * NN + n];
        const float of0v = Of[((b * 2 + 0) * NUMM + mI) * NN + n];
        const float of1v = Of[((b * 2 + 1) * NUMM + mI) * NN + n];
        const float pfg  = Pf[b * NN + aIdx];

        const f4* yp = (const f4*)(ws + (size_t)(b * NN + n) * 32 + c0);
        const f4* zp = (const f4*)(ws + ZOFS + (size_t)(b * NN + aIdx) * 32 + c0);
        f4 y0 = yp[0], y1 = yp[1], z0 = zp[0], z1 = zp[1];

        // invariant reads (loop-variant addresses via io -> stay in loop)
        const f4 wo0a = *(const f4*)&w1t[c0 + 4 * io];
        const f4 wo0b = *(const f4*)&w1t[c0 + 4 + 4 * io];
        const f4 wo1a = *(const f4*)&w1t[32 + c0 + 4 * io];
        const f4 wo1b = *(const f4*)&w1t[32 + c0 + 4 + 4 * io];

        // ---- layer 1: h1 = gelu(Y+Z+of terms) -> directly the B fragment ----
        float x[8];
#pragma unroll
        for (int j = 0; j < 4; j++) {
            x[j]     = fmaf(of1v, wo1a[j], fmaf(of0v, wo0a[j], y0[j] + z0[j]));
            x[4 + j] = fmaf(of1v, wo1b[j], fmaf(of0v, wo0b[j], y1[j] + z1[j]));
        }
#pragma unroll
        for (int j = 0; j < 8; j++) x[j] = gelu_fast(x[j]);
        UV Bv;
#pragma unroll
        for (int p = 0; p < 4; p++) Bv.u[p] = pack2(x[2 * p], x[2 * p + 1]);

        // ---- layer 2 ----
        f4 bt00 = *(const f4*)&btl[0 * 32 + 4 * quad + 4 * io];
        f4 bt01 = *(const f4*)&btl[0 * 32 + 16 + 4 * quad + 4 * io];
        short8 A0l = *(const short8*)&wfrag[0][0][1][lane + io][0];
        short8 A0h = *(const short8*)&wfrag[0][0][0][lane + io][0];
        short8 A1l = *(const short8*)&wfrag[0][1][1][lane + io][0];
        short8 A1h = *(const short8*)&wfrag[0][1][0][lane + io][0];
        f4 acc0 = mm16(A0l, Bv.v, bt00);
        acc0    = mm16(A0h, Bv.v, acc0);
        f4 acc1 = mm16(A1l, Bv.v, bt01);
        acc1    = mm16(A1h, Bv.v, acc1);
        float h2c[8];
#pragma unroll
        for (int r = 0; r < 4; r++) {
            h2c[r]     = gelu_fast(acc0[r]);
            h2c[4 + r] = gelu_fast(acc1[r]);
        }
        // C -> B: publish both tiles, select by target hiT after the shuffle
        {
            unsigned lo0 = pack2(h2c[0], h2c[1]), lo1 = pack2(h2c[2], h2c[3]);
            unsigned hi0 = pack2(h2c[4], h2c[5]), hi1 = pack2(h2c[6], h2c[7]);
            unsigned a0s0 = __shfl(lo0, s0, 64), b0s0 = __shfl(hi0, s0, 64);
            unsigned a1s0 = __shfl(lo1, s0, 64), b1s0 = __shfl(hi1, s0, 64);
            unsigned a0s1 = __shfl(lo0, s1, 64), b0s1 = __shfl(hi0, s1, 64);
            unsigned a1s1 = __shfl(lo1, s1, 64), b1s1 = __shfl(hi1, s1, 64);
            Bv.u[0] = hiT ? b0s0 : a0s0;
            Bv.u[1] = hiT ? b1s0 : a1s0;
            Bv.u[2] = hiT ? b0s1 : a0s1;
            Bv.u[3] = hiT ? b1s1 : a1s1;
        }

        // ---- layer 3 ----
        f4 bt10 = *(const f4*)&btl[1 * 32 + 4 * quad + 4 * io];
        f4 bt11 = *(const f4*)&btl[1 * 32 + 16 + 4 * quad + 4 * io];
        A0l = *(const short8*)&wfrag[1][0][1][lane + io][0];
        A0h = *(const short8*)&wfrag[1][0][0][lane + io][0];
        A1l = *(const short8*)&wfrag[1][1][1][lane + io][0];
        A1h = *(const short8*)&wfrag[1][1][0][lane + io][0];
        acc0 = mm16(A0l, Bv.v, bt10);
        acc0 = mm16(A0h, Bv.v, acc0);
        acc1 = mm16(A1l, Bv.v, bt11);
        acc1 = mm16(A1h, Bv.v, acc1);
        {
            float g0 = gelu_fast(acc0[0]), g1_ = gelu_fast(acc0[1]);
            float g2_ = gelu_fast(acc0[2]), g3_ = gelu_fast(acc0[3]);
            float g4_ = gelu_fast(acc1[0]), g5 = gelu_fast(acc1[1]);
            float g6 = gelu_fast(acc1[2]), g7 = gelu_fast(acc1[3]);
            unsigned lo0 = pack2(g0, g1_), lo1 = pack2(g2_, g3_);
            unsigned hi0 = pack2(g4_, g5), hi1 = pack2(g6, g7);
            unsigned a0s0 = __shfl(lo0, s0, 64), b0s0 = __shfl(hi0, s0, 64);
            unsigned a1s0 = __shfl(lo1, s0, 64), b1s0 = __shfl(hi1, s0, 64);
            unsigned a0s1 = __shfl(lo0, s1, 64), b0s1 = __shfl(hi0, s1, 64);
            unsigned a1s1 = __shfl(lo1, s1, 64), b1s1 = __shfl(hi1, s1, 64);
            Bv.u[0] = hiT ? b0s0 : a0s0;
            Bv.u[1] = hiT ? b1s0 : a1s0;
            Bv.u[2] = hiT ? b0s1 : a0s1;
            Bv.u[3] = hiT ? b1s1 : a1s1;
        }

        // ---- layer 4 + residual + head (all in C layout) ----
        f4 bt20 = *(const f4*)&btl[2 * 32 + 4 * quad + 4 * io];
        f4 bt21 = *(const f4*)&btl[2 * 32 + 16 + 4 * quad + 4 * io];
        A0l = *(const short8*)&wfrag[2][0][1][lane + io][0];
        A0h = *(const short8*)&wfrag[2][0][0][lane + io][0];
        A1l = *(const short8*)&wfrag[2][1][1][lane + io][0];
        A1h = *(const short8*)&wfrag[2][1][0][lane + io][0];
        acc0 = mm16(A0l, Bv.v, bt20);
        acc0 = mm16(A0h, Bv.v, acc0);
        acc1 = mm16(A1l, Bv.v, bt21);
        acc1 = mm16(A1h, Bv.v, acc1);

        const f4 wA0 = *(const f4*)&wch[0 * 32 + 4 * quad + 4 * io];
        const f4 wA1 = *(const f4*)&wch[0 * 32 + 16 + 4 * quad + 4 * io];
        const f4 wB0 = *(const f4*)&wch[1 * 32 + 4 * quad + 4 * io];
        const f4 wB1 = *(const f4*)&wch[1 * 32 + 16 + 4 * quad + 4 * io];
        const f4 wO0 = *(const f4*)&wch[2 * 32 + 4 * quad + 4 * io];
        const f4 wO1 = *(const f4*)&wch[2 * 32 + 16 + 4 * quad + 4 * io];

        float pa = 0.0f, pb = 0.0f, po = 0.0f;
#pragma unroll
        for (int r = 0; r < 4; r++) {
            float xf0 = gelu_fast(h2c[r]     + acc0[r]);
            float xf1 = gelu_fast(h2c[4 + r] + acc1[r]);
            pa = fmaf(wA0[r], xf0, pa);  pa = fmaf(wA1[r], xf1, pa);
            pb = fmaf(wB0[r], xf0, pb);  pb = fmaf(wB1[r], xf1, pb);
            po = fmaf(wO0[r], xf0, po);  po = fmaf(wO1[r], xf1, po);
        }
        pa += __shfl_xor(pa, 16, 64);  pa += __shfl_xor(pa, 32, 64);
        pb += __shfl_xor(pb, 16, 64);  pb += __shfl_xor(pb, 32, 64);
        po += __shfl_xor(po, 16, 64);  po += __shfl_xor(po, 32, 64);
        const float alpha = pa + bcs[0];
        const float beta_ = pb + bcs[1];
        const float omega = po + bcs[2];
        const float val = fmaf(alpha + 1.0f, pfg, beta_);

        // softmax over the 16 m's
        float mx = omega;
#pragma unroll
        for (int s = 1; s < 16; s <<= 1) mx = fmaxf(mx, __shfl_xor(mx, s, 64));
        const float e = __expf(omega - mx);
        float S = e, T = val * e;
#pragma unroll
        for (int s = 1; s < 16; s <<= 1) {
            S += __shfl_xor(S, s, 64);
            T += __shfl_xor(T, s, 64);
        }
        if (lane == 0) out[b * NN + n] = T / S;
    }
}

// ---- launcher ---------------------------------------------------------------
extern "C" void kernel_launch(void* const* d_in, const int* in_sizes, int n_in,
                              void* d_out, int out_size, void* d_ws, size_t ws_size,
                              hipStream_t stream) {
    const float* If    = (const float*)d_in[0];
    const float* Pf    = (const float*)d_in[1];
    const float* Of    = (const float*)d_in[2];
    const int*   args  = (const int*)d_in[3];
    const float* W1    = (const float*)d_in[4];
    const float* g1    = (const float*)d_in[5];
    const float* b1    = (const float*)d_in[6];
    const float* m1    = (const float*)d_in[7];
    const float* v1    = (const float*)d_in[8];
    const float* W2    = (const float*)d_in[9];
    const float* g2    = (const float*)d_in[10];
    const float* b2    = (const float*)d_in[11];
    const float* m2    = (const float*)d_in[12];
    const float* v2    = (const float*)d_in[13];
    const float* W3    = (const float*)d_in[14];
    const float* g3    = (const float*)d_in[15];
    const float* b3    = (const float*)d_in[16];
    const float* m3    = (const float*)d_in[17];
    const float* v3    = (const float*)d_in[18];
    const float* W4    = (const float*)d_in[19];
    const float* g4    = (const float*)d_in[20];
    const float* b4    = (const float*)d_in[21];
    const float* m4    = (const float*)d_in[22];
    const float* v4    = (const float*)d_in[23];
    const float* Wc    = (const float*)d_in[24];
    const float* bc    = (const float*)d_in[25];

    float* ws  = (float*)d_ws;
    float* out = (float*)d_out;

    yz_kernel<<<(BB * NN) / 64, 256, 0, stream>>>(
        If, Pf, W1, g1, b1, m1, v1, ws);

    main_kernel<<<(BB * NN) / 16, 256, 0, stream>>>(
        Pf, Of, args,
        W1, g1, v1,
        W2, g2, b2, m2, v2,
        W3, g3, b3, m3, v3,
        W4, g4, b4, m4, v4,
        Wc, bc, ws, out);
}